// Round 1
// baseline (89.093 us; speedup 1.0000x reference)
//
#include <hip/hip_runtime.h>

#define PATCH 8
#define BATCH 16
#define H 128
#define W 128
#define HW (H * W)          // 16384
#define NK 256              // (H/PATCH)*(W/PATCH)
#define BLOCKS_PER_BATCH 64 // 16384 queries / 256 threads

__global__ __launch_bounds__(256) void gsa_kernel(
    const float* __restrict__ x,
    const float* __restrict__ wq, const float* __restrict__ bq,
    const float* __restrict__ wk, const float* __restrict__ bk,
    const float* __restrict__ wv, const float* __restrict__ bv,
    const float* __restrict__ conv_w, const float* __restrict__ conv_b,
    float* __restrict__ out)
{
    __shared__ float k_lds[NK];
    __shared__ float v_lds[NK];
    __shared__ float cw[64];
    __shared__ float red[8];   // 4 wave maxes, 4 wave mins

    const int tid   = threadIdx.x;
    const int b     = blockIdx.x >> 6;   // 64 blocks per batch
    const int chunk = blockIdx.x & 63;

    // stage conv weights (8x8) in LDS
    if (tid < 64) cw[tid] = conv_w[tid];
    __syncthreads();

    // ---- phase 1: each thread computes one downsampled patch j = tid ----
    const int ph = tid >> 4;
    const int pw = tid & 15;
    const float* xb = x + b * HW;
    const float* pbase = xb + (ph * PATCH) * W + pw * PATCH;

    float ds = 0.f;
    #pragma unroll
    for (int r = 0; r < PATCH; ++r) {
        const float4 a0 = *reinterpret_cast<const float4*>(pbase + r * W);
        const float4 a1 = *reinterpret_cast<const float4*>(pbase + r * W + 4);
        const float* cr = &cw[r * 8];
        ds = fmaf(a0.x, cr[0], ds); ds = fmaf(a0.y, cr[1], ds);
        ds = fmaf(a0.z, cr[2], ds); ds = fmaf(a0.w, cr[3], ds);
        ds = fmaf(a1.x, cr[4], ds); ds = fmaf(a1.y, cr[5], ds);
        ds = fmaf(a1.z, cr[6], ds); ds = fmaf(a1.w, cr[7], ds);
    }
    ds += conv_b[0];

    const float kj = fmaf(ds, wk[0], bk[0]);
    const float vj = fmaf(ds, wv[0], bv[0]);
    k_lds[tid] = kj;
    v_lds[tid] = vj;

    // ---- phase 2: block-wide kmax / kmin (for closed-form row max) ----
    float kmax = kj, kmin = kj;
    #pragma unroll
    for (int off = 32; off > 0; off >>= 1) {
        kmax = fmaxf(kmax, __shfl_xor(kmax, off));
        kmin = fminf(kmin, __shfl_xor(kmin, off));
    }
    const int wave = tid >> 6;
    if ((tid & 63) == 0) { red[wave] = kmax; red[4 + wave] = kmin; }
    __syncthreads();   // also publishes k_lds / v_lds
    kmax = fmaxf(fmaxf(red[0], red[1]), fmaxf(red[2], red[3]));
    kmin = fminf(fminf(red[4], red[5]), fminf(red[6], red[7]));

    // ---- phase 3: per-query single-pass softmax·v ----
    // row max of q*k_j over j is max(q*kmax, q*kmin); fold log2(e) into q
    const int i = chunk * 256 + tid;
    const float LOG2E = 1.4426950408889634f;
    const float ql = fmaf(xb[i], wq[0], bq[0]) * LOG2E;
    const float ml = fmaxf(ql * kmax, ql * kmin);

    float sum = 0.f, acc = 0.f;
    #pragma unroll 8
    for (int j = 0; j < NK; ++j) {
        const float e = exp2f(fmaf(ql, k_lds[j], -ml));  // v_exp_f32
        sum += e;
        acc = fmaf(e, v_lds[j], acc);
    }
    out[b * HW + i] = acc / sum;
}

extern "C" void kernel_launch(void* const* d_in, const int* in_sizes, int n_in,
                              void* d_out, int out_size, void* d_ws, size_t ws_size,
                              hipStream_t stream) {
    const float* x      = (const float*)d_in[0];
    const float* wq     = (const float*)d_in[1];
    const float* bq     = (const float*)d_in[2];
    const float* wk     = (const float*)d_in[3];
    const float* bk     = (const float*)d_in[4];
    const float* wv     = (const float*)d_in[5];
    const float* bv     = (const float*)d_in[6];
    const float* conv_w = (const float*)d_in[7];
    const float* conv_b = (const float*)d_in[8];
    float* out = (float*)d_out;

    dim3 grid(BATCH * BLOCKS_PER_BATCH);   // 1024
    dim3 block(256);
    gsa_kernel<<<grid, block, 0, stream>>>(x, wq, bq, wk, bk, wv, bv,
                                           conv_w, conv_b, out);
}

// Round 5
// 81.621 us; speedup vs baseline: 1.0916x; 1.0916x over previous
//
#include <hip/hip_runtime.h>

#define PATCH 8
#define BATCH 16
#define H 128
#define W 128
#define HW (H * W)          // 16384
#define NK 256              // (H/PATCH)*(W/PATCH)
#define BLOCKS_PER_BATCH 32 // 2 queries per thread: 32*256*2 = 16384
#define QPB 512             // queries per block

#if __has_builtin(__builtin_amdgcn_exp2f)
#define EXP2(x) __builtin_amdgcn_exp2f(x)
#else
#define EXP2(x) exp2f(x)
#endif

__global__ __launch_bounds__(256) void gsa_kernel(
    const float* __restrict__ x,
    const float* __restrict__ wq, const float* __restrict__ bq,
    const float* __restrict__ wk, const float* __restrict__ bk,
    const float* __restrict__ wv, const float* __restrict__ bv,
    const float* __restrict__ conv_w, const float* __restrict__ conv_b,
    float* __restrict__ out)
{
    // kv4[m] = (k_{2m}, k_{2m+1}, v_{2m}, v_{2m+1})
    __shared__ float4 kv4[NK / 2];
    __shared__ float cw[64];
    __shared__ float red[8];   // 4 wave maxes, 4 wave mins

    const int tid   = threadIdx.x;
    const int b     = blockIdx.x >> 5;   // 32 blocks per batch
    const int chunk = blockIdx.x & 31;

    if (tid < 64) cw[tid] = conv_w[tid];
    __syncthreads();

    // ---- phase 1: each thread computes one downsampled patch j = tid ----
    const int ph = tid >> 4;
    const int pw = tid & 15;
    const float* xb = x + b * HW;
    const float* pbase = xb + (ph * PATCH) * W + pw * PATCH;

    float ds = 0.f;
    #pragma unroll
    for (int r = 0; r < PATCH; ++r) {
        const float4 a0 = *reinterpret_cast<const float4*>(pbase + r * W);
        const float4 a1 = *reinterpret_cast<const float4*>(pbase + r * W + 4);
        const float* cr = &cw[r * 8];
        ds = fmaf(a0.x, cr[0], ds); ds = fmaf(a0.y, cr[1], ds);
        ds = fmaf(a0.z, cr[2], ds); ds = fmaf(a0.w, cr[3], ds);
        ds = fmaf(a1.x, cr[4], ds); ds = fmaf(a1.y, cr[5], ds);
        ds = fmaf(a1.z, cr[6], ds); ds = fmaf(a1.w, cr[7], ds);
    }
    ds += conv_b[0];

    const float kj = fmaf(ds, wk[0], bk[0]);
    const float vj = fmaf(ds, wv[0], bv[0]);
    // scatter into the interleaved float4 layout (two b32 writes / thread)
    float* kvf = reinterpret_cast<float*>(kv4);
    kvf[(tid >> 1) * 4 + (tid & 1)]     = kj;
    kvf[(tid >> 1) * 4 + 2 + (tid & 1)] = vj;

    // ---- phase 2: block-wide kmax / kmin (closed-form row max) ----
    float kmax = kj, kmin = kj;
    #pragma unroll
    for (int off = 32; off > 0; off >>= 1) {
        kmax = fmaxf(kmax, __shfl_xor(kmax, off));
        kmin = fminf(kmin, __shfl_xor(kmin, off));
    }
    const int wave = tid >> 6;
    if ((tid & 63) == 0) { red[wave] = kmax; red[4 + wave] = kmin; }
    __syncthreads();   // also publishes kv4
    kmax = fmaxf(fmaxf(red[0], red[1]), fmaxf(red[2], red[3]));
    kmin = fminf(fminf(red[4], red[5]), fminf(red[6], red[7]));

    // ---- phase 3: 2 queries per thread, single-pass softmax·v ----
    const float LOG2E = 1.4426950408889634f;
    const float wq0 = wq[0], bq0 = bq[0];
    const int i0 = chunk * QPB + tid;
    const int i1 = i0 + 256;
    const float ql0 = fmaf(xb[i0], wq0, bq0) * LOG2E;
    const float ql1 = fmaf(xb[i1], wq0, bq0) * LOG2E;
    const float nml0 = -fmaxf(ql0 * kmax, ql0 * kmin);
    const float nml1 = -fmaxf(ql1 * kmax, ql1 * kmin);

    float s0a = 0.f, s0b = 0.f, a0a = 0.f, a0b = 0.f;
    float s1a = 0.f, s1b = 0.f, a1a = 0.f, a1b = 0.f;

    #pragma unroll 4
    for (int m = 0; m < NK / 2; ++m) {
        const float4 t = kv4[m];              // k0,k1,v0,v1 (LDS broadcast)
        const float e00 = EXP2(fmaf(ql0, t.x, nml0));
        const float e01 = EXP2(fmaf(ql0, t.y, nml0));
        const float e10 = EXP2(fmaf(ql1, t.x, nml1));
        const float e11 = EXP2(fmaf(ql1, t.y, nml1));
        s0a += e00; a0a = fmaf(e00, t.z, a0a);
        s0b += e01; a0b = fmaf(e01, t.w, a0b);
        s1a += e10; a1a = fmaf(e10, t.z, a1a);
        s1b += e11; a1b = fmaf(e11, t.w, a1b);
    }

    out[b * HW + i0] = (a0a + a0b) / (s0a + s0b);
    out[b * HW + i1] = (a1a + a1b) / (s1a + s1b);
}

extern "C" void kernel_launch(void* const* d_in, const int* in_sizes, int n_in,
                              void* d_out, int out_size, void* d_ws, size_t ws_size,
                              hipStream_t stream) {
    const float* x      = (const float*)d_in[0];
    const float* wq     = (const float*)d_in[1];
    const float* bq     = (const float*)d_in[2];
    const float* wk     = (const float*)d_in[3];
    const float* bk     = (const float*)d_in[4];
    const float* wv     = (const float*)d_in[5];
    const float* bv     = (const float*)d_in[6];
    const float* conv_w = (const float*)d_in[7];
    const float* conv_b = (const float*)d_in[8];
    float* out = (float*)d_out;

    dim3 grid(BATCH * BLOCKS_PER_BATCH);   // 512
    dim3 block(256);
    gsa_kernel<<<grid, block, 0, stream>>>(x, wq, bq, wk, bk, wv, bv,
                                           conv_w, conv_b, out);
}